// Round 6
// baseline (154.715 us; speedup 1.0000x reference)
//
#include <hip/hip_runtime.h>

#define LEVEL_DIM 8
#define CDIM 32
#define NCELLS (CDIM*CDIM*CDIM)   // 32768 morton-ordered cells
#define NGROUPS (NCELLS/8)        // 4096 groups of 2x2x2 cells

// slab geometry for a 2x2x2-cell group (coverage: s0 = min((2g*(R-1))>>5, R-S))
//   L0: R=16  S=3  rows 27    base 0
//   L1: R=32  S=4  rows 64    base 27
//   L2: R=64  S=6  rows 216   base 91
//   L3: R=128 S=10 rows 1000  base 307
// rows stored as 8 packed bf16 channels = 16B
#define SLAB_ROWS 1307            // * 16B = 20912 B

typedef float    f32x4 __attribute__((ext_vector_type(4)));
typedef unsigned u32x4 __attribute__((ext_vector_type(4)));

__device__ __forceinline__ unsigned part1by2(unsigned x) {
    x &= 0x3ff;
    x = (x | (x << 16)) & 0x030000FF;
    x = (x | (x << 8))  & 0x0300F00F;
    x = (x | (x << 4))  & 0x030C30C3;
    x = (x | (x << 2))  & 0x09249249;
    return x;
}
__device__ __forceinline__ unsigned compact1by2(unsigned x) {
    x &= 0x09249249;
    x = (x | (x >> 2))  & 0x030C30C3;
    x = (x | (x >> 4))  & 0x0300F00F;
    x = (x | (x >> 8))  & 0x030000FF;
    x = (x | (x >> 16)) & 0x000003FF;
    return x;
}

__device__ __forceinline__ int cell_of(float x, float y, float z) {
    int cx = min(CDIM - 1, max(0, (int)(x * (float)CDIM)));
    int cy = min(CDIM - 1, max(0, (int)(y * (float)CDIM)));
    int cz = min(CDIM - 1, max(0, (int)(z * (float)CDIM)));
    return (int)(part1by2(cx) | (part1by2(cy) << 1) | (part1by2(cz) << 2));
}

// round-to-nearest-even f32 -> bf16, two packed into one dword (a=lo, b=hi)
__device__ __forceinline__ unsigned pk_bf16(float a, float b) {
    unsigned ua = __float_as_uint(a), ub = __float_as_uint(b);
    ua += 0x7fffu + ((ua >> 16) & 1u);
    ub += 0x7fffu + ((ub >> 16) & 1u);
    return (ua >> 16) | (ub & 0xffff0000u);
}

__global__ __launch_bounds__(256) void nv_hist(
    const float* __restrict__ in, int* __restrict__ hist,
    unsigned* __restrict__ rank, int B)
{
    const int b = blockIdx.x * 256 + threadIdx.x;
    if (b >= B) return;
    const float x = in[3 * b], y = in[3 * b + 1], z = in[3 * b + 2];
    rank[b] = (unsigned)atomicAdd(&hist[cell_of(x, y, z)], 1);
}

// in-place exclusive scan of NCELLS ints, single workgroup
__global__ __launch_bounds__(1024) void nv_scan(int* __restrict__ cell)
{
    __shared__ int lds[1024];
    const int tid = threadIdx.x;
    const int base = tid * (NCELLS / 1024);   // 32 per thread
    int v[NCELLS / 1024];
    int s = 0;
    #pragma unroll
    for (int e = 0; e < NCELLS / 1024; ++e) { v[e] = cell[base + e]; s += v[e]; }
    lds[tid] = s;
    __syncthreads();
    for (int off = 1; off < 1024; off <<= 1) {
        int t = 0;
        if (tid >= off) t = lds[tid - off];
        __syncthreads();
        if (tid >= off) lds[tid] += t;
        __syncthreads();
    }
    int run = lds[tid] - s;
    #pragma unroll
    for (int e = 0; e < NCELLS / 1024; ++e) { cell[base + e] = run; run += v[e]; }
}

__global__ __launch_bounds__(256) void nv_scatter(
    const float* __restrict__ in, const int* __restrict__ starts,
    const unsigned* __restrict__ rank, f32x4* __restrict__ sorted, int B)
{
    const int b = blockIdx.x * 256 + threadIdx.x;
    if (b >= B) return;
    const float x = in[3 * b], y = in[3 * b + 1], z = in[3 * b + 2];
    const int pos = starts[cell_of(x, y, z)] + (int)rank[b];
    f32x4 v = { x, y, z, __uint_as_float((unsigned)b) };
    __builtin_nontemporal_store(v, &sorted[pos]);
}

// ---- group encode ----

template<int R, int S, int BASE, int TOFF>
__device__ __forceinline__ void stage_level(
    const float* __restrict__ emb, unsigned* slab,
    int s0x, int s0y, int s0z, int tid)
{
    const float* tbl = emb + (size_t)TOFF * LEVEL_DIM;
    constexpr int ROWS = S * S * S;
    #pragma unroll
    for (int t0 = 0; t0 < ROWS; t0 += 256) {
        const int t = t0 + tid;
        if (t < ROWS) {
            const int lx = t % S;
            const int tm = t / S;
            const int ly = tm % S;
            const int lz = tm / S;
            const float* src = tbl +
                ((size_t)((s0z + lz) * R + (s0y + ly)) * R + (s0x + lx)) * LEVEL_DIM;
            const f32x4 a = *(const f32x4*)src;
            const f32x4 b = *(const f32x4*)(src + 4);
            u32x4 d = { pk_bf16(a.x, a.y), pk_bf16(a.z, a.w),
                        pk_bf16(b.x, b.y), pk_bf16(b.z, b.w) };
            *(u32x4*)&slab[(BASE + t) * 4] = d;
        }
    }
}

__device__ __forceinline__ void fma_row(float w, u32x4 d, float* acc) {
    acc[0] = fmaf(w, __uint_as_float(d.x << 16),         acc[0]);
    acc[1] = fmaf(w, __uint_as_float(d.x & 0xffff0000u), acc[1]);
    acc[2] = fmaf(w, __uint_as_float(d.y << 16),         acc[2]);
    acc[3] = fmaf(w, __uint_as_float(d.y & 0xffff0000u), acc[3]);
    acc[4] = fmaf(w, __uint_as_float(d.z << 16),         acc[4]);
    acc[5] = fmaf(w, __uint_as_float(d.z & 0xffff0000u), acc[5]);
    acc[6] = fmaf(w, __uint_as_float(d.w << 16),         acc[6]);
    acc[7] = fmaf(w, __uint_as_float(d.w & 0xffff0000u), acc[7]);
}

template<int R, int S, int BASE>
__device__ __forceinline__ void enc_level(
    const unsigned* slab, int s0x, int s0y, int s0z,
    float x, float y, float z, float* accp)
{
    const float scale = (float)(R - 1);
    const float px = x * scale, py = y * scale, pz = z * scale;
    const float gx = floorf(px), gy = floorf(py), gz = floorf(pz);
    const float fx = px - gx, fy = py - gy, fz = pz - gz;
    const int ix = (int)gx, iy = (int)gy, iz = (int)gz;

    const int ix0 = min(max(ix, 0), R - 1);
    const int ix1 = min(max(ix + 1, 0), R - 1);
    const int iy0 = min(max(iy, 0), R - 1);
    const int iy1 = min(max(iy + 1, 0), R - 1);
    const int iz0 = min(max(iz, 0), R - 1);
    const int iz1 = min(max(iz + 1, 0), R - 1);

    const int lx0 = ix0 - s0x, lx1 = ix1 - s0x;
    const int ly0 = iy0 - s0y, ly1 = iy1 - s0y;
    const int lz0 = iz0 - s0z, lz1 = iz1 - s0z;

    const float wx0 = 1.0f - fx, wx1 = fx;

    float acc[8];
    #pragma unroll
    for (int c = 0; c < 8; ++c) acc[c] = 0.0f;

    #pragma unroll
    for (int kk = 0; kk < 2; ++kk) {
        const int   lz = kk ? lz1 : lz0;
        const float wz = kk ? fz : (1.0f - fz);
        #pragma unroll
        for (int jj = 0; jj < 2; ++jj) {
            const int   ly = jj ? ly1 : ly0;
            const float wy = jj ? fy : (1.0f - fy);

            const int rb = BASE + (lz * S + ly) * S;
            const u32x4 d0 = *(const u32x4*)&slab[(rb + lx0) * 4];
            const u32x4 d1 = *(const u32x4*)&slab[(rb + lx1) * 4];

            fma_row((wx0 * wy) * wz, d0, acc);
            fma_row((wx1 * wy) * wz, d1, acc);
        }
    }
    #pragma unroll
    for (int c = 0; c < 8; ++c) accp[c] = acc[c];
}

__global__ __launch_bounds__(256) void nv_encode_group(
    const f32x4* __restrict__ sorted,
    const int* __restrict__ starts,     // exclusive cell starts (unmutated)
    const float* __restrict__ emb,
    float* __restrict__ out,
    int B)
{
    __shared__ __align__(16) unsigned slab[SLAB_ROWS * 4];   // 20912 B (bf16-packed)
    __shared__ __align__(16) float obuf[4][16 * 36];         // 9216 B, 144B rows

    // XCD swizzle: each XCD gets a contiguous morton octant of groups
    int grp = (int)blockIdx.x;
    grp = (grp & 7) * (NGROUPS / 8) + (grp >> 3);

    const int c0 = grp << 3;
    const int start = starts[c0];
    const int end   = (c0 + 8 < NCELLS) ? starts[c0 + 8] : B;
    if (start >= end) return;

    const int gx = (int)compact1by2((unsigned)grp);
    const int gy = (int)compact1by2((unsigned)grp >> 1);
    const int gz = (int)compact1by2((unsigned)grp >> 2);

    // slab bases per level: s0 = min((2g*(R-1))>>5, R-S)
    const int s0x0 = min((gx * 30)  >> 5, 13),  s0y0 = min((gy * 30)  >> 5, 13),  s0z0 = min((gz * 30)  >> 5, 13);
    const int s0x1 = min((gx * 62)  >> 5, 28),  s0y1 = min((gy * 62)  >> 5, 28),  s0z1 = min((gz * 62)  >> 5, 28);
    const int s0x2 = min((gx * 126) >> 5, 58),  s0y2 = min((gy * 126) >> 5, 58),  s0z2 = min((gz * 126) >> 5, 58);
    const int s0x3 = min((gx * 254) >> 5, 118), s0y3 = min((gy * 254) >> 5, 118), s0z3 = min((gz * 254) >> 5, 118);

    const int tid = threadIdx.x;
    stage_level<16,  3,  0,   0>     (emb, slab, s0x0, s0y0, s0z0, tid);
    stage_level<32,  4,  27,  4096>  (emb, slab, s0x1, s0y1, s0z1, tid);
    stage_level<64,  6,  91,  36864> (emb, slab, s0x2, s0y2, s0z2, tid);
    stage_level<128, 10, 307, 299008>(emb, slab, s0x3, s0y3, s0z3, tid);
    __syncthreads();

    const int wave = tid >> 6;
    const int lane = tid & 63;
    float* wbuf = &obuf[wave][0];

    for (int p0 = start + wave * 64; p0 < end; p0 += 256) {
        const int p = p0 + lane;
        const bool valid = p < end;

        float acc[32];
        unsigned ob = 0;
        if (valid) {
            const f32x4 s = __builtin_nontemporal_load(&sorted[p]);
            ob = __float_as_uint(s.w);
            enc_level<16,  3,  0>  (slab, s0x0, s0y0, s0z0, s.x, s.y, s.z, &acc[0]);
            enc_level<32,  4,  27> (slab, s0x1, s0y1, s0z1, s.x, s.y, s.z, &acc[8]);
            enc_level<64,  6,  91> (slab, s0x2, s0y2, s0z2, s.x, s.y, s.z, &acc[16]);
            enc_level<128, 10, 307>(slab, s0x3, s0y3, s0z3, s.x, s.y, s.z, &acc[24]);
        }

        // transpose 16 points/pass through LDS; store with 8 lanes per point
        #pragma unroll
        for (int pass = 0; pass < 4; ++pass) {
            // WAR guard vs previous pass's reads
            asm volatile("s_waitcnt lgkmcnt(0)" ::: "memory");
            if (valid && (lane >> 4) == pass) {
                const int q = lane & 15;
                #pragma unroll
                for (int k = 0; k < 8; ++k)
                    *(f32x4*)&wbuf[q * 36 + k * 4] = *(const f32x4*)&acc[k * 4];
            }
            asm volatile("s_waitcnt lgkmcnt(0)" ::: "memory");
            #pragma unroll
            for (int j = 0; j < 2; ++j) {
                const int i = pass * 16 + j * 8 + (lane >> 3);   // point slot in wave
                const unsigned obi = __shfl(ob, i);
                if (p0 + i < end) {
                    const f32x4 v = *(const f32x4*)
                        &wbuf[(i - pass * 16) * 36 + (lane & 7) * 4];
                    __builtin_nontemporal_store(
                        v, (f32x4*)(out + (size_t)obi * 32 + (lane & 7) * 4));
                }
            }
        }
    }
}

// ---- fallback direct kernel (ws too small) ----
__global__ __launch_bounds__(256) void nv_encode_direct(
    const float* __restrict__ in,
    const float* __restrict__ emb,
    float* __restrict__ out,
    int B)
{
    const int i = blockIdx.x * 256 + threadIdx.x;
    if (i >= B) return;
    const float x = in[3 * i], y = in[3 * i + 1], z = in[3 * i + 2];
    float* op = out + (size_t)i * 32;

    const int RES[4] = {16, 32, 64, 128};
    const int OFF[4] = {0, 4096, 36864, 299008};

    #pragma unroll
    for (int l = 0; l < 4; ++l) {
        const int R = RES[l];
        const float scale = (float)(R - 1);
        const float px = x * scale, py = y * scale, pz = z * scale;
        const float gxf = floorf(px), gyf = floorf(py), gzf = floorf(pz);
        const float fx = px - gxf, fy = py - gyf, fz = pz - gzf;
        const int ix = (int)gxf, iy = (int)gyf, iz = (int)gzf;
        const int ix0 = min(max(ix, 0), R - 1), ix1 = min(max(ix + 1, 0), R - 1);
        const int iy0 = min(max(iy, 0), R - 1), iy1 = min(max(iy + 1, 0), R - 1);
        const int iz0 = min(max(iz, 0), R - 1), iz1 = min(max(iz + 1, 0), R - 1);
        const float* tbl = emb + (size_t)OFF[l] * LEVEL_DIM;
        const float wx0 = 1.0f - fx, wx1 = fx;
        float acc[8];
        #pragma unroll
        for (int c = 0; c < 8; ++c) acc[c] = 0.0f;
        #pragma unroll
        for (int kk = 0; kk < 2; ++kk) {
            const int zz = kk ? iz1 : iz0;
            const float wz = kk ? fz : (1.0f - fz);
            #pragma unroll
            for (int jj = 0; jj < 2; ++jj) {
                const int yy = jj ? iy1 : iy0;
                const float wy = jj ? fy : (1.0f - fy);
                const size_t rowbase = ((size_t)zz * R + yy) * (size_t)R;
                const float* r0 = tbl + (rowbase + ix0) * LEVEL_DIM;
                const float* r1 = tbl + (rowbase + ix1) * LEVEL_DIM;
                const float w0 = (wx0 * wy) * wz;
                const float w1 = (wx1 * wy) * wz;
                const float4 a0 = *(const float4*)(r0);
                const float4 a1 = *(const float4*)(r0 + 4);
                const float4 b0 = *(const float4*)(r1);
                const float4 b1 = *(const float4*)(r1 + 4);
                acc[0] = fmaf(w0, a0.x, acc[0]); acc[1] = fmaf(w0, a0.y, acc[1]);
                acc[2] = fmaf(w0, a0.z, acc[2]); acc[3] = fmaf(w0, a0.w, acc[3]);
                acc[4] = fmaf(w0, a1.x, acc[4]); acc[5] = fmaf(w0, a1.y, acc[5]);
                acc[6] = fmaf(w0, a1.z, acc[6]); acc[7] = fmaf(w0, a1.w, acc[7]);
                acc[0] = fmaf(w1, b0.x, acc[0]); acc[1] = fmaf(w1, b0.y, acc[1]);
                acc[2] = fmaf(w1, b0.z, acc[2]); acc[3] = fmaf(w1, b0.w, acc[3]);
                acc[4] = fmaf(w1, b1.x, acc[4]); acc[5] = fmaf(w1, b1.y, acc[5]);
                acc[6] = fmaf(w1, b1.z, acc[6]); acc[7] = fmaf(w1, b1.w, acc[7]);
            }
        }
        *(float4*)(op + l * 8)     = make_float4(acc[0], acc[1], acc[2], acc[3]);
        *(float4*)(op + l * 8 + 4) = make_float4(acc[4], acc[5], acc[6], acc[7]);
    }
}

extern "C" void kernel_launch(void* const* d_in, const int* in_sizes, int n_in,
                              void* d_out, int out_size, void* d_ws, size_t ws_size,
                              hipStream_t stream) {
    const float* in  = (const float*)d_in[0];
    const float* emb = (const float*)d_in[1];
    float* out = (float*)d_out;

    const int B = in_sizes[0] / 3;
    const int block = 256;
    const int grid = (B + block - 1) / block;

    const size_t hist_bytes = (size_t)NCELLS * sizeof(int);        // 128 KiB
    const size_t rank_bytes = (size_t)B * sizeof(unsigned);        // 4 MiB
    const size_t need = hist_bytes + rank_bytes + (size_t)B * sizeof(f32x4);

    if (ws_size >= need) {
        int*      hist   = (int*)d_ws;                                    // -> starts after scan
        unsigned* rank   = (unsigned*)((char*)d_ws + hist_bytes);
        f32x4*    sorted = (f32x4*)((char*)d_ws + hist_bytes + rank_bytes);

        (void)hipMemsetAsync(hist, 0, hist_bytes, stream);
        nv_hist<<<grid, block, 0, stream>>>(in, hist, rank, B);
        nv_scan<<<1, 1024, 0, stream>>>(hist);
        nv_scatter<<<grid, block, 0, stream>>>(in, hist, rank, sorted, B);
        nv_encode_group<<<NGROUPS, 256, 0, stream>>>(sorted, hist, emb, out, B);
    } else {
        nv_encode_direct<<<grid, block, 0, stream>>>(in, emb, out, B);
    }
}

// Round 7
// 129.901 us; speedup vs baseline: 1.1910x; 1.1910x over previous
//
#include <hip/hip_runtime.h>

#define LEVEL_DIM 8
#define CDIM 32
#define NCELLS (CDIM*CDIM*CDIM)   // 32768 morton-ordered cells
#define NGROUPS (NCELLS/8)        // 4096 groups of 2x2x2 cells

// slab geometry for a 2x2x2-cell group (coverage: s0 = min((2g*(R-1))>>5, R-S))
//   L0: R=16  S=3  rows 27    base 0
//   L1: R=32  S=4  rows 64    base 27
//   L2: R=64  S=6  rows 216   base 91
//   L3: R=128 S=10 rows 1000  base 307
// rows stored as 8 packed bf16 channels = 16B
#define SLAB_ROWS 1307            // * 16B = 20912 B

typedef float    f32x4 __attribute__((ext_vector_type(4)));
typedef unsigned u32x4 __attribute__((ext_vector_type(4)));

__device__ __forceinline__ unsigned part1by2(unsigned x) {
    x &= 0x3ff;
    x = (x | (x << 16)) & 0x030000FF;
    x = (x | (x << 8))  & 0x0300F00F;
    x = (x | (x << 4))  & 0x030C30C3;
    x = (x | (x << 2))  & 0x09249249;
    return x;
}
__device__ __forceinline__ unsigned compact1by2(unsigned x) {
    x &= 0x09249249;
    x = (x | (x >> 2))  & 0x030C30C3;
    x = (x | (x >> 4))  & 0x0300F00F;
    x = (x | (x >> 8))  & 0x030000FF;
    x = (x | (x >> 16)) & 0x000003FF;
    return x;
}

__device__ __forceinline__ int cell_of(float x, float y, float z) {
    int cx = min(CDIM - 1, max(0, (int)(x * (float)CDIM)));
    int cy = min(CDIM - 1, max(0, (int)(y * (float)CDIM)));
    int cz = min(CDIM - 1, max(0, (int)(z * (float)CDIM)));
    return (int)(part1by2(cx) | (part1by2(cy) << 1) | (part1by2(cz) << 2));
}

// round-to-nearest-even f32 -> bf16, two packed into one dword (a=lo, b=hi)
__device__ __forceinline__ unsigned pk_bf16(float a, float b) {
    unsigned ua = __float_as_uint(a), ub = __float_as_uint(b);
    ua += 0x7fffu + ((ua >> 16) & 1u);
    ub += 0x7fffu + ((ub >> 16) & 1u);
    return (ua >> 16) | (ub & 0xffff0000u);
}

__global__ __launch_bounds__(256) void nv_hist(
    const float* __restrict__ in, int* __restrict__ hist,
    unsigned* __restrict__ rank, int B)
{
    const int b = blockIdx.x * 256 + threadIdx.x;
    if (b >= B) return;
    const float x = in[3 * b], y = in[3 * b + 1], z = in[3 * b + 2];
    rank[b] = (unsigned)atomicAdd(&hist[cell_of(x, y, z)], 1);
}

// in-place exclusive scan of NCELLS ints, single workgroup
__global__ __launch_bounds__(1024) void nv_scan(int* __restrict__ cell)
{
    __shared__ int lds[1024];
    const int tid = threadIdx.x;
    const int base = tid * (NCELLS / 1024);   // 32 per thread
    int v[NCELLS / 1024];
    int s = 0;
    #pragma unroll
    for (int e = 0; e < NCELLS / 1024; ++e) { v[e] = cell[base + e]; s += v[e]; }
    lds[tid] = s;
    __syncthreads();
    for (int off = 1; off < 1024; off <<= 1) {
        int t = 0;
        if (tid >= off) t = lds[tid - off];
        __syncthreads();
        if (tid >= off) lds[tid] += t;
        __syncthreads();
    }
    int run = lds[tid] - s;
    #pragma unroll
    for (int e = 0; e < NCELLS / 1024; ++e) { cell[base + e] = run; run += v[e]; }
}

__global__ __launch_bounds__(256) void nv_scatter(
    const float* __restrict__ in, const int* __restrict__ starts,
    const unsigned* __restrict__ rank, f32x4* __restrict__ sorted, int B)
{
    const int b = blockIdx.x * 256 + threadIdx.x;
    if (b >= B) return;
    const float x = in[3 * b], y = in[3 * b + 1], z = in[3 * b + 2];
    const int pos = starts[cell_of(x, y, z)] + (int)rank[b];
    f32x4 v = { x, y, z, __uint_as_float((unsigned)b) };
    sorted[pos] = v;   // cached store: L2 write-combining, encode re-reads it
}

// ---- group encode ----

template<int R, int S, int BASE, int TOFF>
__device__ __forceinline__ void stage_level(
    const float* __restrict__ emb, unsigned* slab,
    int s0x, int s0y, int s0z, int tid)
{
    const float* tbl = emb + (size_t)TOFF * LEVEL_DIM;
    constexpr int ROWS = S * S * S;
    #pragma unroll
    for (int t0 = 0; t0 < ROWS; t0 += 256) {
        const int t = t0 + tid;
        if (t < ROWS) {
            const int lx = t % S;
            const int tm = t / S;
            const int ly = tm % S;
            const int lz = tm / S;
            const float* src = tbl +
                ((size_t)((s0z + lz) * R + (s0y + ly)) * R + (s0x + lx)) * LEVEL_DIM;
            const f32x4 a = *(const f32x4*)src;
            const f32x4 b = *(const f32x4*)(src + 4);
            u32x4 d = { pk_bf16(a.x, a.y), pk_bf16(a.z, a.w),
                        pk_bf16(b.x, b.y), pk_bf16(b.z, b.w) };
            *(u32x4*)&slab[(BASE + t) * 4] = d;
        }
    }
}

__device__ __forceinline__ void fma_row(float w, u32x4 d, float* acc) {
    acc[0] = fmaf(w, __uint_as_float(d.x << 16),         acc[0]);
    acc[1] = fmaf(w, __uint_as_float(d.x & 0xffff0000u), acc[1]);
    acc[2] = fmaf(w, __uint_as_float(d.y << 16),         acc[2]);
    acc[3] = fmaf(w, __uint_as_float(d.y & 0xffff0000u), acc[3]);
    acc[4] = fmaf(w, __uint_as_float(d.z << 16),         acc[4]);
    acc[5] = fmaf(w, __uint_as_float(d.z & 0xffff0000u), acc[5]);
    acc[6] = fmaf(w, __uint_as_float(d.w << 16),         acc[6]);
    acc[7] = fmaf(w, __uint_as_float(d.w & 0xffff0000u), acc[7]);
}

template<int R, int S, int BASE>
__device__ __forceinline__ void enc_level(
    const unsigned* slab, int s0x, int s0y, int s0z,
    float x, float y, float z, float* accp)
{
    const float scale = (float)(R - 1);
    const float px = x * scale, py = y * scale, pz = z * scale;
    const float gx = floorf(px), gy = floorf(py), gz = floorf(pz);
    const float fx = px - gx, fy = py - gy, fz = pz - gz;
    const int ix = (int)gx, iy = (int)gy, iz = (int)gz;

    const int ix0 = min(max(ix, 0), R - 1);
    const int ix1 = min(max(ix + 1, 0), R - 1);
    const int iy0 = min(max(iy, 0), R - 1);
    const int iy1 = min(max(iy + 1, 0), R - 1);
    const int iz0 = min(max(iz, 0), R - 1);
    const int iz1 = min(max(iz + 1, 0), R - 1);

    const int lx0 = ix0 - s0x, lx1 = ix1 - s0x;
    const int ly0 = iy0 - s0y, ly1 = iy1 - s0y;
    const int lz0 = iz0 - s0z, lz1 = iz1 - s0z;

    const float wx0 = 1.0f - fx, wx1 = fx;

    float acc[8];
    #pragma unroll
    for (int c = 0; c < 8; ++c) acc[c] = 0.0f;

    #pragma unroll
    for (int kk = 0; kk < 2; ++kk) {
        const int   lz = kk ? lz1 : lz0;
        const float wz = kk ? fz : (1.0f - fz);
        #pragma unroll
        for (int jj = 0; jj < 2; ++jj) {
            const int   ly = jj ? ly1 : ly0;
            const float wy = jj ? fy : (1.0f - fy);

            const int rb = BASE + (lz * S + ly) * S;
            const u32x4 d0 = *(const u32x4*)&slab[(rb + lx0) * 4];
            const u32x4 d1 = *(const u32x4*)&slab[(rb + lx1) * 4];

            fma_row((wx0 * wy) * wz, d0, acc);
            fma_row((wx1 * wy) * wz, d1, acc);
        }
    }
    #pragma unroll
    for (int c = 0; c < 8; ++c) accp[c] = acc[c];
}

__global__ __launch_bounds__(256) void nv_encode_group(
    const f32x4* __restrict__ sorted,
    const int* __restrict__ starts,     // exclusive cell starts (unmutated)
    const float* __restrict__ emb,
    float* __restrict__ out,
    int B)
{
    __shared__ __align__(16) unsigned slab[SLAB_ROWS * 4];   // 20912 B (bf16-packed)
    __shared__ __align__(16) float obuf[4][8 * 36];          // 4608 B, 144B rows

    // XCD swizzle: each XCD gets a contiguous morton octant of groups
    int grp = (int)blockIdx.x;
    grp = (grp & 7) * (NGROUPS / 8) + (grp >> 3);

    const int c0 = grp << 3;
    const int start = starts[c0];
    const int end   = (c0 + 8 < NCELLS) ? starts[c0 + 8] : B;
    if (start >= end) return;

    const int gx = (int)compact1by2((unsigned)grp);
    const int gy = (int)compact1by2((unsigned)grp >> 1);
    const int gz = (int)compact1by2((unsigned)grp >> 2);

    // slab bases per level: s0 = min((2g*(R-1))>>5, R-S)
    const int s0x0 = min((gx * 30)  >> 5, 13),  s0y0 = min((gy * 30)  >> 5, 13),  s0z0 = min((gz * 30)  >> 5, 13);
    const int s0x1 = min((gx * 62)  >> 5, 28),  s0y1 = min((gy * 62)  >> 5, 28),  s0z1 = min((gz * 62)  >> 5, 28);
    const int s0x2 = min((gx * 126) >> 5, 58),  s0y2 = min((gy * 126) >> 5, 58),  s0z2 = min((gz * 126) >> 5, 58);
    const int s0x3 = min((gx * 254) >> 5, 118), s0y3 = min((gy * 254) >> 5, 118), s0z3 = min((gz * 254) >> 5, 118);

    const int tid = threadIdx.x;
    stage_level<16,  3,  0,   0>     (emb, slab, s0x0, s0y0, s0z0, tid);
    stage_level<32,  4,  27,  4096>  (emb, slab, s0x1, s0y1, s0z1, tid);
    stage_level<64,  6,  91,  36864> (emb, slab, s0x2, s0y2, s0z2, tid);
    stage_level<128, 10, 307, 299008>(emb, slab, s0x3, s0y3, s0z3, tid);
    __syncthreads();

    const int wave = tid >> 6;
    const int lane = tid & 63;
    float* wbuf = &obuf[wave][0];

    for (int p0 = start + wave * 64; p0 < end; p0 += 256) {
        const int p = p0 + lane;
        const bool valid = p < end;

        float acc[32];
        unsigned ob = 0;
        if (valid) {
            const f32x4 s = sorted[p];     // cached: L2/L3 hit from scatter
            ob = __float_as_uint(s.w);
            enc_level<16,  3,  0>  (slab, s0x0, s0y0, s0z0, s.x, s.y, s.z, &acc[0]);
            enc_level<32,  4,  27> (slab, s0x1, s0y1, s0z1, s.x, s.y, s.z, &acc[8]);
            enc_level<64,  6,  91> (slab, s0x2, s0y2, s0z2, s.x, s.y, s.z, &acc[16]);
            enc_level<128, 10, 307>(slab, s0x3, s0y3, s0z3, s.x, s.y, s.z, &acc[24]);
        }

        // transpose 8 points/pass through LDS; store with 8 lanes per point
        #pragma unroll
        for (int pass = 0; pass < 8; ++pass) {
            // WAR guard vs previous pass's reads (cross-lane via LDS, same wave)
            asm volatile("s_waitcnt lgkmcnt(0)" ::: "memory");
            if (valid && (lane >> 3) == pass) {
                const int q = lane & 7;
                #pragma unroll
                for (int k = 0; k < 8; ++k)
                    *(f32x4*)&wbuf[q * 36 + k * 4] = *(const f32x4*)&acc[k * 4];
            }
            asm volatile("s_waitcnt lgkmcnt(0)" ::: "memory");
            const int i = pass * 8 + (lane >> 3);   // point slot in wave
            const unsigned obi = __shfl(ob, i);
            if (p0 + i < end) {
                const f32x4 v = *(const f32x4*)
                    &wbuf[(lane >> 3) * 36 + (lane & 7) * 4];
                __builtin_nontemporal_store(
                    v, (f32x4*)(out + (size_t)obi * 32 + (lane & 7) * 4));
            }
        }
    }
}

// ---- fallback direct kernel (ws too small) ----
__global__ __launch_bounds__(256) void nv_encode_direct(
    const float* __restrict__ in,
    const float* __restrict__ emb,
    float* __restrict__ out,
    int B)
{
    const int i = blockIdx.x * 256 + threadIdx.x;
    if (i >= B) return;
    const float x = in[3 * i], y = in[3 * i + 1], z = in[3 * i + 2];
    float* op = out + (size_t)i * 32;

    const int RES[4] = {16, 32, 64, 128};
    const int OFF[4] = {0, 4096, 36864, 299008};

    #pragma unroll
    for (int l = 0; l < 4; ++l) {
        const int R = RES[l];
        const float scale = (float)(R - 1);
        const float px = x * scale, py = y * scale, pz = z * scale;
        const float gxf = floorf(px), gyf = floorf(py), gzf = floorf(pz);
        const float fx = px - gxf, fy = py - gyf, fz = pz - gzf;
        const int ix = (int)gxf, iy = (int)gyf, iz = (int)gzf;
        const int ix0 = min(max(ix, 0), R - 1), ix1 = min(max(ix + 1, 0), R - 1);
        const int iy0 = min(max(iy, 0), R - 1), iy1 = min(max(iy + 1, 0), R - 1);
        const int iz0 = min(max(iz, 0), R - 1), iz1 = min(max(iz + 1, 0), R - 1);
        const float* tbl = emb + (size_t)OFF[l] * LEVEL_DIM;
        const float wx0 = 1.0f - fx, wx1 = fx;
        float acc[8];
        #pragma unroll
        for (int c = 0; c < 8; ++c) acc[c] = 0.0f;
        #pragma unroll
        for (int kk = 0; kk < 2; ++kk) {
            const int zz = kk ? iz1 : iz0;
            const float wz = kk ? fz : (1.0f - fz);
            #pragma unroll
            for (int jj = 0; jj < 2; ++jj) {
                const int yy = jj ? iy1 : iy0;
                const float wy = jj ? fy : (1.0f - fy);
                const size_t rowbase = ((size_t)zz * R + yy) * (size_t)R;
                const float* r0 = tbl + (rowbase + ix0) * LEVEL_DIM;
                const float* r1 = tbl + (rowbase + ix1) * LEVEL_DIM;
                const float w0 = (wx0 * wy) * wz;
                const float w1 = (wx1 * wy) * wz;
                const float4 a0 = *(const float4*)(r0);
                const float4 a1 = *(const float4*)(r0 + 4);
                const float4 b0 = *(const float4*)(r1);
                const float4 b1 = *(const float4*)(r1 + 4);
                acc[0] = fmaf(w0, a0.x, acc[0]); acc[1] = fmaf(w0, a0.y, acc[1]);
                acc[2] = fmaf(w0, a0.z, acc[2]); acc[3] = fmaf(w0, a0.w, acc[3]);
                acc[4] = fmaf(w0, a1.x, acc[4]); acc[5] = fmaf(w0, a1.y, acc[5]);
                acc[6] = fmaf(w0, a1.z, acc[6]); acc[7] = fmaf(w0, a1.w, acc[7]);
                acc[0] = fmaf(w1, b0.x, acc[0]); acc[1] = fmaf(w1, b0.y, acc[1]);
                acc[2] = fmaf(w1, b0.z, acc[2]); acc[3] = fmaf(w1, b0.w, acc[3]);
                acc[4] = fmaf(w1, b1.x, acc[4]); acc[5] = fmaf(w1, b1.y, acc[5]);
                acc[6] = fmaf(w1, b1.z, acc[6]); acc[7] = fmaf(w1, b1.w, acc[7]);
            }
        }
        *(float4*)(op + l * 8)     = make_float4(acc[0], acc[1], acc[2], acc[3]);
        *(float4*)(op + l * 8 + 4) = make_float4(acc[4], acc[5], acc[6], acc[7]);
    }
}

extern "C" void kernel_launch(void* const* d_in, const int* in_sizes, int n_in,
                              void* d_out, int out_size, void* d_ws, size_t ws_size,
                              hipStream_t stream) {
    const float* in  = (const float*)d_in[0];
    const float* emb = (const float*)d_in[1];
    float* out = (float*)d_out;

    const int B = in_sizes[0] / 3;
    const int block = 256;
    const int grid = (B + block - 1) / block;

    const size_t hist_bytes = (size_t)NCELLS * sizeof(int);        // 128 KiB
    const size_t rank_bytes = (size_t)B * sizeof(unsigned);        // 4 MiB
    const size_t need = hist_bytes + rank_bytes + (size_t)B * sizeof(f32x4);

    if (ws_size >= need) {
        int*      hist   = (int*)d_ws;                                    // -> starts after scan
        unsigned* rank   = (unsigned*)((char*)d_ws + hist_bytes);
        f32x4*    sorted = (f32x4*)((char*)d_ws + hist_bytes + rank_bytes);

        (void)hipMemsetAsync(hist, 0, hist_bytes, stream);
        nv_hist<<<grid, block, 0, stream>>>(in, hist, rank, B);
        nv_scan<<<1, 1024, 0, stream>>>(hist);
        nv_scatter<<<grid, block, 0, stream>>>(in, hist, rank, sorted, B);
        nv_encode_group<<<NGROUPS, 256, 0, stream>>>(sorted, hist, emb, out, B);
    } else {
        nv_encode_direct<<<grid, block, 0, stream>>>(in, emb, out, B);
    }
}

// Round 8
// 126.588 us; speedup vs baseline: 1.2222x; 1.0262x over previous
//
#include <hip/hip_runtime.h>

#define LEVEL_DIM 8
#define CDIM 32
#define NCELLS (CDIM*CDIM*CDIM)   // 32768 morton-ordered cells
#define NGROUPS (NCELLS/8)        // 4096 groups of 2x2x2 cells

// slab geometry for a 2x2x2-cell group (coverage: s0 = min((2g*(R-1))>>5, R-S))
//   L0: R=16  S=3  rows 27    base 0
//   L1: R=32  S=4  rows 64    base 27
//   L2: R=64  S=6  rows 216   base 91
//   L3: R=128 S=10 rows 1000  base 307
// rows stored as 8 packed bf16 channels = 16B
#define SLAB_ROWS 1307            // * 16B = 20912 B

typedef float    f32x4 __attribute__((ext_vector_type(4)));
typedef unsigned u32x4 __attribute__((ext_vector_type(4)));

__device__ __forceinline__ unsigned part1by2(unsigned x) {
    x &= 0x3ff;
    x = (x | (x << 16)) & 0x030000FF;
    x = (x | (x << 8))  & 0x0300F00F;
    x = (x | (x << 4))  & 0x030C30C3;
    x = (x | (x << 2))  & 0x09249249;
    return x;
}
__device__ __forceinline__ unsigned compact1by2(unsigned x) {
    x &= 0x09249249;
    x = (x | (x >> 2))  & 0x030C30C3;
    x = (x | (x >> 4))  & 0x0300F00F;
    x = (x | (x >> 8))  & 0x030000FF;
    x = (x | (x >> 16)) & 0x000003FF;
    return x;
}

__device__ __forceinline__ int cell_of(float x, float y, float z) {
    int cx = min(CDIM - 1, max(0, (int)(x * (float)CDIM)));
    int cy = min(CDIM - 1, max(0, (int)(y * (float)CDIM)));
    int cz = min(CDIM - 1, max(0, (int)(z * (float)CDIM)));
    return (int)(part1by2(cx) | (part1by2(cy) << 1) | (part1by2(cz) << 2));
}

// round-to-nearest-even f32 -> bf16, two packed into one dword (a=lo, b=hi)
__device__ __forceinline__ unsigned pk_bf16(float a, float b) {
    unsigned ua = __float_as_uint(a), ub = __float_as_uint(b);
    ua += 0x7fffu + ((ua >> 16) & 1u);
    ub += 0x7fffu + ((ub >> 16) & 1u);
    return (ua >> 16) | (ub & 0xffff0000u);
}

__global__ __launch_bounds__(256) void nv_hist(
    const float* __restrict__ in, int* __restrict__ hist,
    unsigned* __restrict__ cellrank, int B)
{
    const int b = blockIdx.x * 256 + threadIdx.x;
    if (b >= B) return;
    const float x = in[3 * b], y = in[3 * b + 1], z = in[3 * b + 2];
    const int c = cell_of(x, y, z);
    const unsigned r = (unsigned)atomicAdd(&hist[c], 1);
    cellrank[b] = (unsigned)c | (r << 15);     // rank < 2^17 (avg 32/cell)
}

// in-place exclusive scan of NCELLS ints, single workgroup
__global__ __launch_bounds__(1024) void nv_scan(int* __restrict__ cell)
{
    __shared__ int lds[1024];
    const int tid = threadIdx.x;
    const int base = tid * (NCELLS / 1024);   // 32 per thread
    int v[NCELLS / 1024];
    int s = 0;
    #pragma unroll
    for (int e = 0; e < NCELLS / 1024; ++e) { v[e] = cell[base + e]; s += v[e]; }
    lds[tid] = s;
    __syncthreads();
    for (int off = 1; off < 1024; off <<= 1) {
        int t = 0;
        if (tid >= off) t = lds[tid - off];
        __syncthreads();
        if (tid >= off) lds[tid] += t;
        __syncthreads();
    }
    int run = lds[tid] - s;
    #pragma unroll
    for (int e = 0; e < NCELLS / 1024; ++e) { cell[base + e] = run; run += v[e]; }
}

__global__ __launch_bounds__(256) void nv_scatter(
    const float* __restrict__ in, const int* __restrict__ starts,
    const unsigned* __restrict__ cellrank, f32x4* __restrict__ sorted, int B)
{
    const int b = blockIdx.x * 256 + threadIdx.x;
    if (b >= B) return;
    const float x = in[3 * b], y = in[3 * b + 1], z = in[3 * b + 2];
    const unsigned cr = cellrank[b];
    const int pos = starts[cr & 0x7fffu] + (int)(cr >> 15);
    f32x4 v = { x, y, z, __uint_as_float((unsigned)b) };
    sorted[pos] = v;   // cached store: L2 write-combining, encode re-reads it
}

// ---- group encode ----

template<int R, int S, int BASE, int TOFF>
__device__ __forceinline__ void stage_level(
    const float* __restrict__ emb, unsigned* slab,
    int s0x, int s0y, int s0z, int tid)
{
    const float* tbl = emb + (size_t)TOFF * LEVEL_DIM;
    constexpr int ROWS = S * S * S;
    #pragma unroll
    for (int t0 = 0; t0 < ROWS; t0 += 256) {
        const int t = t0 + tid;
        if (t < ROWS) {
            const int lx = t % S;
            const int tm = t / S;
            const int ly = tm % S;
            const int lz = tm / S;
            const float* src = tbl +
                ((size_t)((s0z + lz) * R + (s0y + ly)) * R + (s0x + lx)) * LEVEL_DIM;
            const f32x4 a = *(const f32x4*)src;
            const f32x4 b = *(const f32x4*)(src + 4);
            u32x4 d = { pk_bf16(a.x, a.y), pk_bf16(a.z, a.w),
                        pk_bf16(b.x, b.y), pk_bf16(b.z, b.w) };
            *(u32x4*)&slab[(BASE + t) * 4] = d;
        }
    }
}

__device__ __forceinline__ void fma_row(float w, u32x4 d, float* acc) {
    acc[0] = fmaf(w, __uint_as_float(d.x << 16),         acc[0]);
    acc[1] = fmaf(w, __uint_as_float(d.x & 0xffff0000u), acc[1]);
    acc[2] = fmaf(w, __uint_as_float(d.y << 16),         acc[2]);
    acc[3] = fmaf(w, __uint_as_float(d.y & 0xffff0000u), acc[3]);
    acc[4] = fmaf(w, __uint_as_float(d.z << 16),         acc[4]);
    acc[5] = fmaf(w, __uint_as_float(d.z & 0xffff0000u), acc[5]);
    acc[6] = fmaf(w, __uint_as_float(d.w << 16),         acc[6]);
    acc[7] = fmaf(w, __uint_as_float(d.w & 0xffff0000u), acc[7]);
}

template<int R, int S, int BASE>
__device__ __forceinline__ void enc_level(
    const unsigned* slab, int s0x, int s0y, int s0z,
    float x, float y, float z, float* accp)
{
    const float scale = (float)(R - 1);
    const float px = x * scale, py = y * scale, pz = z * scale;
    const float gx = floorf(px), gy = floorf(py), gz = floorf(pz);
    const float fx = px - gx, fy = py - gy, fz = pz - gz;
    const int ix = (int)gx, iy = (int)gy, iz = (int)gz;

    const int ix0 = min(max(ix, 0), R - 1);
    const int ix1 = min(max(ix + 1, 0), R - 1);
    const int iy0 = min(max(iy, 0), R - 1);
    const int iy1 = min(max(iy + 1, 0), R - 1);
    const int iz0 = min(max(iz, 0), R - 1);
    const int iz1 = min(max(iz + 1, 0), R - 1);

    const int lx0 = ix0 - s0x, lx1 = ix1 - s0x;
    const int ly0 = iy0 - s0y, ly1 = iy1 - s0y;
    const int lz0 = iz0 - s0z, lz1 = iz1 - s0z;

    const float wx0 = 1.0f - fx, wx1 = fx;

    float acc[8];
    #pragma unroll
    for (int c = 0; c < 8; ++c) acc[c] = 0.0f;

    #pragma unroll
    for (int kk = 0; kk < 2; ++kk) {
        const int   lz = kk ? lz1 : lz0;
        const float wz = kk ? fz : (1.0f - fz);
        #pragma unroll
        for (int jj = 0; jj < 2; ++jj) {
            const int   ly = jj ? ly1 : ly0;
            const float wy = jj ? fy : (1.0f - fy);

            const int rb = BASE + (lz * S + ly) * S;
            const u32x4 d0 = *(const u32x4*)&slab[(rb + lx0) * 4];
            const u32x4 d1 = *(const u32x4*)&slab[(rb + lx1) * 4];

            fma_row((wx0 * wy) * wz, d0, acc);
            fma_row((wx1 * wy) * wz, d1, acc);
        }
    }
    #pragma unroll
    for (int c = 0; c < 8; ++c) accp[c] = acc[c];
}

__global__ __launch_bounds__(256) void nv_encode_group(
    const f32x4* __restrict__ sorted,
    const int* __restrict__ starts,     // exclusive cell starts (unmutated)
    const float* __restrict__ emb,
    float* __restrict__ out,
    int B)
{
    __shared__ __align__(16) unsigned slab[SLAB_ROWS * 4];   // 20912 B (bf16-packed)
    __shared__ __align__(16) float obuf[4][32 * 36];         // 18432 B, 144B rows

    // XCD swizzle: each XCD gets a contiguous morton octant of groups
    int grp = (int)blockIdx.x;
    grp = (grp & 7) * (NGROUPS / 8) + (grp >> 3);

    const int c0 = grp << 3;
    const int start = starts[c0];
    const int end   = (c0 + 8 < NCELLS) ? starts[c0 + 8] : B;
    if (start >= end) return;

    const int gx = (int)compact1by2((unsigned)grp);
    const int gy = (int)compact1by2((unsigned)grp >> 1);
    const int gz = (int)compact1by2((unsigned)grp >> 2);

    // slab bases per level: s0 = min((2g*(R-1))>>5, R-S)
    const int s0x0 = min((gx * 30)  >> 5, 13),  s0y0 = min((gy * 30)  >> 5, 13),  s0z0 = min((gz * 30)  >> 5, 13);
    const int s0x1 = min((gx * 62)  >> 5, 28),  s0y1 = min((gy * 62)  >> 5, 28),  s0z1 = min((gz * 62)  >> 5, 28);
    const int s0x2 = min((gx * 126) >> 5, 58),  s0y2 = min((gy * 126) >> 5, 58),  s0z2 = min((gz * 126) >> 5, 58);
    const int s0x3 = min((gx * 254) >> 5, 118), s0y3 = min((gy * 254) >> 5, 118), s0z3 = min((gz * 254) >> 5, 118);

    const int tid = threadIdx.x;
    stage_level<16,  3,  0,   0>     (emb, slab, s0x0, s0y0, s0z0, tid);
    stage_level<32,  4,  27,  4096>  (emb, slab, s0x1, s0y1, s0z1, tid);
    stage_level<64,  6,  91,  36864> (emb, slab, s0x2, s0y2, s0z2, tid);
    stage_level<128, 10, 307, 299008>(emb, slab, s0x3, s0y3, s0z3, tid);
    __syncthreads();

    const int wave = tid >> 6;
    const int lane = tid & 63;
    float* wbuf = &obuf[wave][0];

    for (int p0 = start + wave * 64; p0 < end; p0 += 256) {
        const int p = p0 + lane;
        const bool valid = p < end;

        float acc[32];
        unsigned ob = 0;
        if (valid) {
            const f32x4 s = sorted[p];     // cached: L2/L3 hit from scatter
            ob = __float_as_uint(s.w);
            enc_level<16,  3,  0>  (slab, s0x0, s0y0, s0z0, s.x, s.y, s.z, &acc[0]);
            enc_level<32,  4,  27> (slab, s0x1, s0y1, s0z1, s.x, s.y, s.z, &acc[8]);
            enc_level<64,  6,  91> (slab, s0x2, s0y2, s0z2, s.x, s.y, s.z, &acc[16]);
            enc_level<128, 10, 307>(slab, s0x3, s0y3, s0z3, s.x, s.y, s.z, &acc[24]);
        }

        // transpose 32 points per half through LDS; store with 8 lanes/point
        #pragma unroll
        for (int h = 0; h < 2; ++h) {
            // WAR guard vs previous half's reads (cross-lane via LDS, same wave)
            asm volatile("s_waitcnt lgkmcnt(0)" ::: "memory");
            if (valid && (lane >> 5) == h) {
                const int q = lane & 31;
                #pragma unroll
                for (int k = 0; k < 8; ++k)
                    *(f32x4*)&wbuf[q * 36 + k * 4] = *(const f32x4*)&acc[k * 4];
            }
            asm volatile("s_waitcnt lgkmcnt(0)" ::: "memory");  // RAW
            #pragma unroll
            for (int j = 0; j < 4; ++j) {
                const int slot = j * 8 + (lane >> 3);    // 0..31
                const int i = h * 32 + slot;             // point slot in wave
                const unsigned obi = __shfl(ob, i);
                if (p0 + i < end) {
                    const f32x4 v = *(const f32x4*)
                        &wbuf[slot * 36 + (lane & 7) * 4];
                    __builtin_nontemporal_store(
                        v, (f32x4*)(out + (size_t)obi * 32 + (lane & 7) * 4));
                }
            }
        }
    }
}

// ---- fallback direct kernel (ws too small) ----
__global__ __launch_bounds__(256) void nv_encode_direct(
    const float* __restrict__ in,
    const float* __restrict__ emb,
    float* __restrict__ out,
    int B)
{
    const int i = blockIdx.x * 256 + threadIdx.x;
    if (i >= B) return;
    const float x = in[3 * i], y = in[3 * i + 1], z = in[3 * i + 2];
    float* op = out + (size_t)i * 32;

    const int RES[4] = {16, 32, 64, 128};
    const int OFF[4] = {0, 4096, 36864, 299008};

    #pragma unroll
    for (int l = 0; l < 4; ++l) {
        const int R = RES[l];
        const float scale = (float)(R - 1);
        const float px = x * scale, py = y * scale, pz = z * scale;
        const float gxf = floorf(px), gyf = floorf(py), gzf = floorf(pz);
        const float fx = px - gxf, fy = py - gyf, fz = pz - gzf;
        const int ix = (int)gxf, iy = (int)gyf, iz = (int)gzf;
        const int ix0 = min(max(ix, 0), R - 1), ix1 = min(max(ix + 1, 0), R - 1);
        const int iy0 = min(max(iy, 0), R - 1), iy1 = min(max(iy + 1, 0), R - 1);
        const int iz0 = min(max(iz, 0), R - 1), iz1 = min(max(iz + 1, 0), R - 1);
        const float* tbl = emb + (size_t)OFF[l] * LEVEL_DIM;
        const float wx0 = 1.0f - fx, wx1 = fx;
        float acc[8];
        #pragma unroll
        for (int c = 0; c < 8; ++c) acc[c] = 0.0f;
        #pragma unroll
        for (int kk = 0; kk < 2; ++kk) {
            const int zz = kk ? iz1 : iz0;
            const float wz = kk ? fz : (1.0f - fz);
            #pragma unroll
            for (int jj = 0; jj < 2; ++jj) {
                const int yy = jj ? iy1 : iy0;
                const float wy = jj ? fy : (1.0f - fy);
                const size_t rowbase = ((size_t)zz * R + yy) * (size_t)R;
                const float* r0 = tbl + (rowbase + ix0) * LEVEL_DIM;
                const float* r1 = tbl + (rowbase + ix1) * LEVEL_DIM;
                const float w0 = (wx0 * wy) * wz;
                const float w1 = (wx1 * wy) * wz;
                const float4 a0 = *(const float4*)(r0);
                const float4 a1 = *(const float4*)(r0 + 4);
                const float4 b0 = *(const float4*)(r1);
                const float4 b1 = *(const float4*)(r1 + 4);
                acc[0] = fmaf(w0, a0.x, acc[0]); acc[1] = fmaf(w0, a0.y, acc[1]);
                acc[2] = fmaf(w0, a0.z, acc[2]); acc[3] = fmaf(w0, a0.w, acc[3]);
                acc[4] = fmaf(w0, a1.x, acc[4]); acc[5] = fmaf(w0, a1.y, acc[5]);
                acc[6] = fmaf(w0, a1.z, acc[6]); acc[7] = fmaf(w0, a1.w, acc[7]);
                acc[0] = fmaf(w1, b0.x, acc[0]); acc[1] = fmaf(w1, b0.y, acc[1]);
                acc[2] = fmaf(w1, b0.z, acc[2]); acc[3] = fmaf(w1, b0.w, acc[3]);
                acc[4] = fmaf(w1, b1.x, acc[4]); acc[5] = fmaf(w1, b1.y, acc[5]);
                acc[6] = fmaf(w1, b1.z, acc[6]); acc[7] = fmaf(w1, b1.w, acc[7]);
            }
        }
        *(float4*)(op + l * 8)     = make_float4(acc[0], acc[1], acc[2], acc[3]);
        *(float4*)(op + l * 8 + 4) = make_float4(acc[4], acc[5], acc[6], acc[7]);
    }
}

extern "C" void kernel_launch(void* const* d_in, const int* in_sizes, int n_in,
                              void* d_out, int out_size, void* d_ws, size_t ws_size,
                              hipStream_t stream) {
    const float* in  = (const float*)d_in[0];
    const float* emb = (const float*)d_in[1];
    float* out = (float*)d_out;

    const int B = in_sizes[0] / 3;
    const int block = 256;
    const int grid = (B + block - 1) / block;

    const size_t hist_bytes = (size_t)NCELLS * sizeof(int);        // 128 KiB
    const size_t rank_bytes = (size_t)B * sizeof(unsigned);        // 4 MiB
    const size_t need = hist_bytes + rank_bytes + (size_t)B * sizeof(f32x4);

    if (ws_size >= need) {
        int*      hist     = (int*)d_ws;                                  // -> starts after scan
        unsigned* cellrank = (unsigned*)((char*)d_ws + hist_bytes);
        f32x4*    sorted   = (f32x4*)((char*)d_ws + hist_bytes + rank_bytes);

        (void)hipMemsetAsync(hist, 0, hist_bytes, stream);
        nv_hist<<<grid, block, 0, stream>>>(in, hist, cellrank, B);
        nv_scan<<<1, 1024, 0, stream>>>(hist);
        nv_scatter<<<grid, block, 0, stream>>>(in, hist, cellrank, sorted, B);
        nv_encode_group<<<NGROUPS, 256, 0, stream>>>(sorted, hist, emb, out, B);
    } else {
        nv_encode_direct<<<grid, block, 0, stream>>>(in, emb, out, B);
    }
}

// Round 9
// 122.041 us; speedup vs baseline: 1.2677x; 1.0373x over previous
//
#include <hip/hip_runtime.h>

#define LEVEL_DIM 8
#define CDIM 32
#define NCELLS (CDIM*CDIM*CDIM)   // 32768 morton-ordered cells
#define NGROUPS (NCELLS/8)        // 4096 groups of 2x2x2 cells

// slab geometry for a 2x2x2-cell group (coverage: s0 = min((2g*(R-1))>>5, R-S))
//   L0: R=16  S=3  rows 27    base 0
//   L1: R=32  S=4  rows 64    base 27
//   L2: R=64  S=6  rows 216   base 91
//   L3: R=128 S=10 rows 1000  base 307
// rows stored as 8 packed bf16 channels = 16B
#define SLAB_ROWS 1307            // * 16B = 20912 B

typedef float    f32x4 __attribute__((ext_vector_type(4)));
typedef unsigned u32x4 __attribute__((ext_vector_type(4)));

__device__ __forceinline__ unsigned part1by2(unsigned x) {
    x &= 0x3ff;
    x = (x | (x << 16)) & 0x030000FF;
    x = (x | (x << 8))  & 0x0300F00F;
    x = (x | (x << 4))  & 0x030C30C3;
    x = (x | (x << 2))  & 0x09249249;
    return x;
}
__device__ __forceinline__ unsigned compact1by2(unsigned x) {
    x &= 0x09249249;
    x = (x | (x >> 2))  & 0x030C30C3;
    x = (x | (x >> 4))  & 0x0300F00F;
    x = (x | (x >> 8))  & 0x030000FF;
    x = (x | (x >> 16)) & 0x000003FF;
    return x;
}

__device__ __forceinline__ int cell_of(float x, float y, float z) {
    int cx = min(CDIM - 1, max(0, (int)(x * (float)CDIM)));
    int cy = min(CDIM - 1, max(0, (int)(y * (float)CDIM)));
    int cz = min(CDIM - 1, max(0, (int)(z * (float)CDIM)));
    return (int)(part1by2(cx) | (part1by2(cy) << 1) | (part1by2(cz) << 2));
}

// round-to-nearest-even f32 -> bf16, two packed into one dword (a=lo, b=hi)
__device__ __forceinline__ unsigned pk_bf16(float a, float b) {
    unsigned ua = __float_as_uint(a), ub = __float_as_uint(b);
    ua += 0x7fffu + ((ua >> 16) & 1u);
    ub += 0x7fffu + ((ub >> 16) & 1u);
    return (ua >> 16) | (ub & 0xffff0000u);
}

__global__ __launch_bounds__(256) void nv_hist(
    const float* __restrict__ in, int* __restrict__ hist,
    unsigned* __restrict__ cellrank, int B)
{
    const int b = blockIdx.x * 256 + threadIdx.x;
    if (b >= B) return;
    const float x = in[3 * b], y = in[3 * b + 1], z = in[3 * b + 2];
    const int c = cell_of(x, y, z);
    const unsigned r = (unsigned)atomicAdd(&hist[c], 1);
    cellrank[b] = (unsigned)c | (r << 15);     // rank < 2^17 (avg 32/cell)
}

// in-place exclusive scan of NCELLS ints, single workgroup
__global__ __launch_bounds__(1024) void nv_scan(int* __restrict__ cell)
{
    __shared__ int lds[1024];
    const int tid = threadIdx.x;
    const int base = tid * (NCELLS / 1024);   // 32 per thread
    int v[NCELLS / 1024];
    int s = 0;
    #pragma unroll
    for (int e = 0; e < NCELLS / 1024; ++e) { v[e] = cell[base + e]; s += v[e]; }
    lds[tid] = s;
    __syncthreads();
    for (int off = 1; off < 1024; off <<= 1) {
        int t = 0;
        if (tid >= off) t = lds[tid - off];
        __syncthreads();
        if (tid >= off) lds[tid] += t;
        __syncthreads();
    }
    int run = lds[tid] - s;
    #pragma unroll
    for (int e = 0; e < NCELLS / 1024; ++e) { cell[base + e] = run; run += v[e]; }
}

__global__ __launch_bounds__(256) void nv_scatter(
    const float* __restrict__ in, const int* __restrict__ starts,
    const unsigned* __restrict__ cellrank, f32x4* __restrict__ sorted, int B)
{
    const int b = blockIdx.x * 256 + threadIdx.x;
    if (b >= B) return;
    const float x = in[3 * b], y = in[3 * b + 1], z = in[3 * b + 2];
    const unsigned cr = cellrank[b];
    const int pos = starts[cr & 0x7fffu] + (int)(cr >> 15);
    f32x4 v = { x, y, z, __uint_as_float((unsigned)b) };
    sorted[pos] = v;   // cached store: L2 write-combining, encode re-reads it
}

// ---- group encode ----

template<int R, int S, int BASE, int TOFF>
__device__ __forceinline__ void stage_level(
    const float* __restrict__ emb, unsigned* slab,
    int s0x, int s0y, int s0z, int tid)
{
    const float* tbl = emb + (size_t)TOFF * LEVEL_DIM;
    constexpr int ROWS = S * S * S;
    #pragma unroll
    for (int t0 = 0; t0 < ROWS; t0 += 256) {
        const int t = t0 + tid;
        if (t < ROWS) {
            const int lx = t % S;
            const int tm = t / S;
            const int ly = tm % S;
            const int lz = tm / S;
            const float* src = tbl +
                ((size_t)((s0z + lz) * R + (s0y + ly)) * R + (s0x + lx)) * LEVEL_DIM;
            const f32x4 a = *(const f32x4*)src;
            const f32x4 b = *(const f32x4*)(src + 4);
            u32x4 d = { pk_bf16(a.x, a.y), pk_bf16(a.z, a.w),
                        pk_bf16(b.x, b.y), pk_bf16(b.z, b.w) };
            *(u32x4*)&slab[(BASE + t) * 4] = d;
        }
    }
}

__global__ __launch_bounds__(256) void nv_encode_group(
    const f32x4* __restrict__ sorted,
    const int* __restrict__ starts,     // exclusive cell starts (unmutated)
    const float* __restrict__ emb,
    float* __restrict__ out,
    int B)
{
    __shared__ __align__(16) unsigned slab[SLAB_ROWS * 4];   // 20912 B (bf16-packed)

    // XCD swizzle: each XCD gets a contiguous morton octant of groups
    int grp = (int)blockIdx.x;
    grp = (grp & 7) * (NGROUPS / 8) + (grp >> 3);

    const int c0 = grp << 3;
    const int start = starts[c0];
    const int end   = (c0 + 8 < NCELLS) ? starts[c0 + 8] : B;
    if (start >= end) return;

    const int gx = (int)compact1by2((unsigned)grp);
    const int gy = (int)compact1by2((unsigned)grp >> 1);
    const int gz = (int)compact1by2((unsigned)grp >> 2);

    // slab bases per level: s0 = min((2g*(R-1))>>5, R-S)
    const int s0x0 = min((gx * 30)  >> 5, 13),  s0y0 = min((gy * 30)  >> 5, 13),  s0z0 = min((gz * 30)  >> 5, 13);
    const int s0x1 = min((gx * 62)  >> 5, 28),  s0y1 = min((gy * 62)  >> 5, 28),  s0z1 = min((gz * 62)  >> 5, 28);
    const int s0x2 = min((gx * 126) >> 5, 58),  s0y2 = min((gy * 126) >> 5, 58),  s0z2 = min((gz * 126) >> 5, 58);
    const int s0x3 = min((gx * 254) >> 5, 118), s0y3 = min((gy * 254) >> 5, 118), s0z3 = min((gz * 254) >> 5, 118);

    const int tid = threadIdx.x;
    stage_level<16,  3,  0,   0>     (emb, slab, s0x0, s0y0, s0z0, tid);
    stage_level<32,  4,  27,  4096>  (emb, slab, s0x1, s0y1, s0z1, tid);
    stage_level<64,  6,  91,  36864> (emb, slab, s0x2, s0y2, s0z2, tid);
    stage_level<128, 10, 307, 299008>(emb, slab, s0x3, s0y3, s0z3, tid);
    __syncthreads();

    // 8 lanes per point: lane ln owns level ln>>1, channels (ln&1)*4..+4.
    // Store is 8 x f32x4 = one contiguous 128B row per point. No obuf.
    const int ln  = tid & 7;
    const int lvl = ln >> 1;
    const int sub = tid >> 3;          // 0..31: point slot within block pass

    #define SEL4(v0,v1,v2,v3) ((lvl & 2) ? ((lvl & 1) ? (v3) : (v2)) \
                                         : ((lvl & 1) ? (v1) : (v0)))
    const float scale = SEL4(15.0f, 31.0f, 63.0f, 127.0f);
    const int   Rm1   = SEL4(15, 31, 63, 127);
    const int   S_    = SEL4(3, 4, 6, 10);
    const int   BASE_ = SEL4(0, 27, 91, 307);
    const int   sx    = SEL4(s0x0, s0x1, s0x2, s0x3);
    const int   sy    = SEL4(s0y0, s0y1, s0y2, s0y3);
    const int   sz    = SEL4(s0z0, s0z1, s0z2, s0z3);
    #undef SEL4
    const int dsel = (ln & 1) * 2;     // dword offset within a 4-dword row

    for (int p = start + sub; p < end; p += 32) {
        const f32x4 s = sorted[p];     // 8 lanes share p -> broadcast line
        const unsigned ob = __float_as_uint(s.w);

        const float px = s.x * scale, py = s.y * scale, pz = s.z * scale;
        const float gpx = floorf(px), gpy = floorf(py), gpz = floorf(pz);
        const float fx = px - gpx, fy = py - gpy, fz = pz - gpz;
        const int ix = (int)gpx, iy = (int)gpy, iz = (int)gpz;

        const int ix0 = min(max(ix, 0), Rm1),     ix1 = min(max(ix + 1, 0), Rm1);
        const int iy0 = min(max(iy, 0), Rm1),     iy1 = min(max(iy + 1, 0), Rm1);
        const int iz0 = min(max(iz, 0), Rm1),     iz1 = min(max(iz + 1, 0), Rm1);

        const int lx0 = ix0 - sx, lx1 = ix1 - sx;
        const int ly0 = iy0 - sy, ly1 = iy1 - sy;
        const int lz0 = iz0 - sz, lz1 = iz1 - sz;

        const float wx0 = 1.0f - fx, wx1 = fx;
        const float wy0 = 1.0f - fy, wy1 = fy;
        const float wz0 = 1.0f - fz, wz1 = fz;

        // row bases for the 4 (z,y) combos
        const int rzy00 = BASE_ + (lz0 * S_ + ly0) * S_;
        const int rzy01 = BASE_ + (lz0 * S_ + ly1) * S_;
        const int rzy10 = BASE_ + (lz1 * S_ + ly0) * S_;
        const int rzy11 = BASE_ + (lz1 * S_ + ly1) * S_;

        float a0 = 0.0f, a1 = 0.0f, a2 = 0.0f, a3 = 0.0f;

        // corner order matches reference CORNERS (x fastest, then y, then z);
        // weight order matches reference prod: ((wx*wy)*wz)
        #define CORNER(rzy, lx, wx, wy, wz) do {                              \
            const uint2 d = *(const uint2*)&slab[((rzy) + (lx)) * 4 + dsel];  \
            const float w = ((wx) * (wy)) * (wz);                             \
            a0 = fmaf(w, __uint_as_float(d.x << 16),         a0);             \
            a1 = fmaf(w, __uint_as_float(d.x & 0xffff0000u), a1);             \
            a2 = fmaf(w, __uint_as_float(d.y << 16),         a2);             \
            a3 = fmaf(w, __uint_as_float(d.y & 0xffff0000u), a3);             \
        } while (0)

        CORNER(rzy00, lx0, wx0, wy0, wz0);
        CORNER(rzy00, lx1, wx1, wy0, wz0);
        CORNER(rzy01, lx0, wx0, wy1, wz0);
        CORNER(rzy01, lx1, wx1, wy1, wz0);
        CORNER(rzy10, lx0, wx0, wy0, wz1);
        CORNER(rzy10, lx1, wx1, wy0, wz1);
        CORNER(rzy11, lx0, wx0, wy1, wz1);
        CORNER(rzy11, lx1, wx1, wy1, wz1);
        #undef CORNER

        const f32x4 r = { a0, a1, a2, a3 };
        __builtin_nontemporal_store(
            r, (f32x4*)(out + (size_t)ob * 32 + ln * 4));
    }
}

// ---- fallback direct kernel (ws too small) ----
__global__ __launch_bounds__(256) void nv_encode_direct(
    const float* __restrict__ in,
    const float* __restrict__ emb,
    float* __restrict__ out,
    int B)
{
    const int i = blockIdx.x * 256 + threadIdx.x;
    if (i >= B) return;
    const float x = in[3 * i], y = in[3 * i + 1], z = in[3 * i + 2];
    float* op = out + (size_t)i * 32;

    const int RES[4] = {16, 32, 64, 128};
    const int OFF[4] = {0, 4096, 36864, 299008};

    #pragma unroll
    for (int l = 0; l < 4; ++l) {
        const int R = RES[l];
        const float scale = (float)(R - 1);
        const float px = x * scale, py = y * scale, pz = z * scale;
        const float gxf = floorf(px), gyf = floorf(py), gzf = floorf(pz);
        const float fx = px - gxf, fy = py - gyf, fz = pz - gzf;
        const int ix = (int)gxf, iy = (int)gyf, iz = (int)gzf;
        const int ix0 = min(max(ix, 0), R - 1), ix1 = min(max(ix + 1, 0), R - 1);
        const int iy0 = min(max(iy, 0), R - 1), iy1 = min(max(iy + 1, 0), R - 1);
        const int iz0 = min(max(iz, 0), R - 1), iz1 = min(max(iz + 1, 0), R - 1);
        const float* tbl = emb + (size_t)OFF[l] * LEVEL_DIM;
        const float wx0 = 1.0f - fx, wx1 = fx;
        float acc[8];
        #pragma unroll
        for (int c = 0; c < 8; ++c) acc[c] = 0.0f;
        #pragma unroll
        for (int kk = 0; kk < 2; ++kk) {
            const int zz = kk ? iz1 : iz0;
            const float wz = kk ? fz : (1.0f - fz);
            #pragma unroll
            for (int jj = 0; jj < 2; ++jj) {
                const int yy = jj ? iy1 : iy0;
                const float wy = jj ? fy : (1.0f - fy);
                const size_t rowbase = ((size_t)zz * R + yy) * (size_t)R;
                const float* r0 = tbl + (rowbase + ix0) * LEVEL_DIM;
                const float* r1 = tbl + (rowbase + ix1) * LEVEL_DIM;
                const float w0 = (wx0 * wy) * wz;
                const float w1 = (wx1 * wy) * wz;
                const float4 a0 = *(const float4*)(r0);
                const float4 a1 = *(const float4*)(r0 + 4);
                const float4 b0 = *(const float4*)(r1);
                const float4 b1 = *(const float4*)(r1 + 4);
                acc[0] = fmaf(w0, a0.x, acc[0]); acc[1] = fmaf(w0, a0.y, acc[1]);
                acc[2] = fmaf(w0, a0.z, acc[2]); acc[3] = fmaf(w0, a0.w, acc[3]);
                acc[4] = fmaf(w0, a1.x, acc[4]); acc[5] = fmaf(w0, a1.y, acc[5]);
                acc[6] = fmaf(w0, a1.z, acc[6]); acc[7] = fmaf(w0, a1.w, acc[7]);
                acc[0] = fmaf(w1, b0.x, acc[0]); acc[1] = fmaf(w1, b0.y, acc[1]);
                acc[2] = fmaf(w1, b0.z, acc[2]); acc[3] = fmaf(w1, b0.w, acc[3]);
                acc[4] = fmaf(w1, b1.x, acc[4]); acc[5] = fmaf(w1, b1.y, acc[5]);
                acc[6] = fmaf(w1, b1.z, acc[6]); acc[7] = fmaf(w1, b1.w, acc[7]);
            }
        }
        *(float4*)(op + l * 8)     = make_float4(acc[0], acc[1], acc[2], acc[3]);
        *(float4*)(op + l * 8 + 4) = make_float4(acc[4], acc[5], acc[6], acc[7]);
    }
}

extern "C" void kernel_launch(void* const* d_in, const int* in_sizes, int n_in,
                              void* d_out, int out_size, void* d_ws, size_t ws_size,
                              hipStream_t stream) {
    const float* in  = (const float*)d_in[0];
    const float* emb = (const float*)d_in[1];
    float* out = (float*)d_out;

    const int B = in_sizes[0] / 3;
    const int block = 256;
    const int grid = (B + block - 1) / block;

    const size_t hist_bytes = (size_t)NCELLS * sizeof(int);        // 128 KiB
    const size_t rank_bytes = (size_t)B * sizeof(unsigned);        // 4 MiB
    const size_t need = hist_bytes + rank_bytes + (size_t)B * sizeof(f32x4);

    if (ws_size >= need) {
        int*      hist     = (int*)d_ws;                                  // -> starts after scan
        unsigned* cellrank = (unsigned*)((char*)d_ws + hist_bytes);
        f32x4*    sorted   = (f32x4*)((char*)d_ws + hist_bytes + rank_bytes);

        (void)hipMemsetAsync(hist, 0, hist_bytes, stream);
        nv_hist<<<grid, block, 0, stream>>>(in, hist, cellrank, B);
        nv_scan<<<1, 1024, 0, stream>>>(hist);
        nv_scatter<<<grid, block, 0, stream>>>(in, hist, cellrank, sorted, B);
        nv_encode_group<<<NGROUPS, 256, 0, stream>>>(sorted, hist, emb, out, B);
    } else {
        nv_encode_direct<<<grid, block, 0, stream>>>(in, emb, out, B);
    }
}